// Round 5
// baseline (72.268 us; speedup 1.0000x reference)
//
#include <hip/hip_runtime.h>
#include <math.h>

#define D    2048
#define S    4096
#define NP   8
#define BLK  256
#define EPSF 1e-12f
#define MARGINF 0.5f

// Workspace layout:
//   [0,        S*4)            uint  counts   -- NEVER zeroed: mod-NP slot trick
//   [S*4,      S*4 + S*NP*4)   int   members
//   [+,        + S*4)          float contribs
//   [+,        + 4)            uint  done     -- re-zeroed by gather each replay
//
// R1/R2 lesson: per-block agent-scope ORDERED atomics (rel/acq_rel fences) emit
// buffer_wbl2/buffer_inv per block -> 200-400us of L2 cache-maintenance.
// R5 approach: zero cache-maintenance sync. contribs stored via RELAXED
// agent-scope atomic store (sc1 write-through to coherence point), ordering via
// raw s_waitcnt vmcnt(0) (waits for store ack -- a wait, not a cache op), then
// RELAXED fetch_add. RMWs are totally ordered at the coherence point, so the
// block seeing old==S-1 knows all other stores are already acked there. Last
// block reads contribs with relaxed sc1 loads (bypass stale caches).
// R3/R4 lesson: the compiler's phase-4 remat reloads are L2-hits and free;
// forcing them live (PIN + occupancy cap) was neutral-to-worse. Keep max occ.

__global__ __launch_bounds__(256) void gather_kernel(const int* __restrict__ labels,
                                                     unsigned int* __restrict__ counts,
                                                     int* __restrict__ members,
                                                     unsigned int* __restrict__ done,
                                                     int B) {
    int i = blockIdx.x * blockDim.x + threadIdx.x;
    if (i == 0) __hip_atomic_store(done, 0u, __ATOMIC_RELAXED, __HIP_MEMORY_SCOPE_AGENT);
    if (i >= B) return;
    int lab = labels[i];
    // counts is poisoned garbage, but each label gets exactly NP atomicAdds ->
    // 8 consecutive return values -> (pos & 7) is a unique slot regardless of the
    // initial value. Slot order is arbitrary; speaker kernel sorts, so the final
    // accumulation order stays deterministic. Saves the zero_counts dispatch.
    unsigned int pos = atomicAdd(&counts[lab], 1u) & (unsigned)(NP - 1);
    members[lab * NP + (int)pos] = i;
}

__global__ __launch_bounds__(BLK) void speaker_kernel(const float* __restrict__ emb,
                                                      const int* __restrict__ members,
                                                      float* __restrict__ contribs,
                                                      unsigned int* __restrict__ done,
                                                      float* __restrict__ out) {
    __shared__ float sm[4][NP];
    __shared__ float sm2[4];
    __shared__ int   last_flag;

    const int s = blockIdx.x;
    const int t = threadIdx.x;
    const int lane = t & 63;
    const int wid  = t >> 6;

    // ---- Prologue: uniform member load + in-register Batcher sort (no LDS, no barriers) ----
    int m[NP];
    #pragma unroll
    for (int k = 0; k < NP; ++k) m[k] = members[s * NP + k];
    // 19-comparator odd-even mergesort network, all indices compile-time constant
    #define CE(a, b) { int lo_ = min(m[a], m[b]); int hi_ = max(m[a], m[b]); m[a] = lo_; m[b] = hi_; }
    CE(0,1) CE(2,3) CE(4,5) CE(6,7)
    CE(0,2) CE(1,3) CE(4,6) CE(5,7)
    CE(1,2) CE(5,6)
    CE(0,4) CE(1,5) CE(2,6) CE(3,7)
    CE(2,4) CE(3,5)
    CE(1,2) CE(3,4) CE(5,6)
    #undef CE

    // ---- Phase 1: issue ALL 16 loads (8 rows x 2 float4) before any use ----
    float4 x0[NP], x1[NP];
    #pragma unroll
    for (int k = 0; k < NP; ++k) {
        const float4* row = (const float4*)(emb + (size_t)m[k] * D);
        x0[k] = row[t];
        x1[k] = row[t + BLK];
    }

    // ---- Phase 2: per-row partial sumsq + wave-level reduce (no barriers) ----
    float ss[NP];
    #pragma unroll
    for (int k = 0; k < NP; ++k) {
        float v = x0[k].x * x0[k].x + x0[k].y * x0[k].y
                + x0[k].z * x0[k].z + x0[k].w * x0[k].w
                + x1[k].x * x1[k].x + x1[k].y * x1[k].y
                + x1[k].z * x1[k].z + x1[k].w * x1[k].w;
        #pragma unroll
        for (int o = 32; o > 0; o >>= 1) v += __shfl_xor(v, o, 64);
        ss[k] = v;
    }

    // ---- Phase 3: one barrier pair for all 8 cross-wave reductions ----
    if (lane == 0) {
        #pragma unroll
        for (int k = 0; k < NP; ++k) sm[wid][k] = ss[k];
    }
    __syncthreads();

    // ---- Phase 4: normalize + accumulate speaker-sum in registers ----
    float4 a0 = make_float4(0.f, 0.f, 0.f, 0.f);
    float4 a1 = make_float4(0.f, 0.f, 0.f, 0.f);
    float selfsum = 0.f;  // sum of ||e_hat||^2 (uniform across threads)
    #pragma unroll
    for (int k = 0; k < NP; ++k) {
        float tot = sm[0][k] + sm[1][k] + sm[2][k] + sm[3][k];
        float inv = rsqrtf(tot + EPSF);
        selfsum += tot * inv * inv;
        a0.x += x0[k].x * inv; a0.y += x0[k].y * inv;
        a0.z += x0[k].z * inv; a0.w += x0[k].w * inv;
        a1.x += x1[k].x * inv; a1.y += x1[k].y * inv;
        a1.z += x1[k].z * inv; a1.w += x1[k].w * inv;
    }

    // ---- Phase 5: ||sum||^2 reduce + write contribution ----
    float nq = a0.x * a0.x + a0.y * a0.y + a0.z * a0.z + a0.w * a0.w
             + a1.x * a1.x + a1.y * a1.y + a1.z * a1.z + a1.w * a1.w;
    #pragma unroll
    for (int o = 32; o > 0; o >>= 1) nq += __shfl_xor(nq, o, 64);
    if (lane == 0) sm2[wid] = nq;
    __syncthreads();

    if (t == 0) {
        float total_nq   = sm2[0] + sm2[1] + sm2[2] + sm2[3];
        float sumpair    = 0.5f * (total_nq - selfsum);       // sum_{i<j} cos sim
        float n_pairs    = (float)(NP * (NP - 1)) * 0.5f;     // 28
        float mean_intra = 1.0f - sumpair / n_pairs;
        float c          = mean_intra - MARGINF;
        float cr         = c > 0.f ? c : 0.f;
        // relaxed agent-scope atomic store: sc1 write-through to coherence point,
        // leaves nothing dirty in this XCD's L2 -> no cache maintenance needed later
        __hip_atomic_store(&contribs[s], cr, __ATOMIC_RELAXED, __HIP_MEMORY_SCOPE_AGENT);
        // ordering via plain wait (store acked at coherence point), NOT a release
        // fence (which would emit buffer_wbl2 -- the R2 disaster)
        asm volatile("s_waitcnt vmcnt(0)" ::: "memory");
        unsigned int old = __hip_atomic_fetch_add(done, 1u, __ATOMIC_RELAXED,
                                                  __HIP_MEMORY_SCOPE_AGENT);
        last_flag = (old == (unsigned)(S - 1)) ? 1 : 0;
    }
    __syncthreads();

    // ---- Last block standing: deterministic final reduction, no fences ----
    if (last_flag) {
        float v = 0.f;
        #pragma unroll
        for (int j = 0; j < S / BLK; ++j)
            v += __hip_atomic_load(&contribs[t + j * BLK], __ATOMIC_RELAXED,
                                   __HIP_MEMORY_SCOPE_AGENT);  // sc1: bypass stale caches
        #pragma unroll
        for (int o = 32; o > 0; o >>= 1) v += __shfl_xor(v, o, 64);
        if (lane == 0) sm2[wid] = v;   // safe: all threads past phase-5 barrier
        __syncthreads();
        if (t == 0) *out = (sm2[0] + sm2[1] + sm2[2] + sm2[3]) / (float)S;
    }
}

extern "C" void kernel_launch(void* const* d_in, const int* in_sizes, int n_in,
                              void* d_out, int out_size, void* d_ws, size_t ws_size,
                              hipStream_t stream) {
    const float* emb    = (const float*)d_in[0];
    const int*   labels = (const int*)d_in[1];
    float*       out    = (float*)d_out;

    char* ws = (char*)d_ws;
    unsigned int* counts   = (unsigned int*)ws;                           // S uints (never zeroed)
    int*          members  = (int*)(ws + (size_t)S * sizeof(int));        // S*NP ints
    float*        contribs = (float*)(ws + (size_t)S * sizeof(int)
                                         + (size_t)S * NP * sizeof(int)); // S floats
    unsigned int* done     = (unsigned int*)(ws + (size_t)S * sizeof(int)
                                                + (size_t)S * NP * sizeof(int)
                                                + (size_t)S * sizeof(float)); // 1 uint

    const int B = in_sizes[1];   // 32768

    gather_kernel<<<(B + 255) / 256, 256, 0, stream>>>(labels, counts, members, done, B);
    speaker_kernel<<<S, BLK, 0, stream>>>(emb, members, contribs, done, out);
}

// Round 6
// 52.726 us; speedup vs baseline: 1.3706x; 1.3706x over previous
//
#include <hip/hip_runtime.h>
#include <math.h>

#define D    2048
#define S    4096
#define NP   8
#define BLK  256
#define EPSF 1e-12f
#define MARGINF 0.5f

// Workspace layout:
//   [0,        S*4)            uint  counts   -- NEVER zeroed: mod-NP slot trick
//   [S*4,      S*4 + S*NP*4)   int   members
//   [+,        + S*4)          float contribs
//
// Session lessons (keep with the kernel):
// - Fused single-kernel tail is DEAD on gfx950: per-block agent-scope sync costs
//   +230us (acq_rel: buffer_inv/block), +112us (release: buffer_wbl2/block),
//   +19us (relaxed sc1 store + vmcnt ack-wait + coherence-point RMW) vs the
//   ~2.5us of a separate reduce dispatch. Kernel boundary = cheapest grid barrier.
// - VGPR_Count=56 => compiler remats the 16 float4 from global in phase 4; those
//   reloads are L2-hits and FREE. Pinning them + occupancy cap (256,4) was
//   neutral-to-worse. Keep max-occupancy codegen.
// - Speaker kernel: 45.5us for 268.4MB demand = 5.9 TB/s = ~94% of the 6.3 TB/s
//   measured machine ceiling (FETCH~131MB, other half L3-served). Roofline.

__global__ __launch_bounds__(256) void gather_kernel(const int* __restrict__ labels,
                                                     unsigned int* __restrict__ counts,
                                                     int* __restrict__ members,
                                                     int B) {
    int i = blockIdx.x * blockDim.x + threadIdx.x;
    if (i >= B) return;
    int lab = labels[i];
    // counts is poisoned garbage, but each label gets exactly NP atomicAdds ->
    // 8 consecutive return values -> (pos & 7) is a unique slot regardless of the
    // initial value. Slot order is arbitrary; speaker kernel sorts, so the final
    // accumulation order stays deterministic. Saves the zero_counts dispatch.
    unsigned int pos = atomicAdd(&counts[lab], 1u) & (unsigned)(NP - 1);
    members[lab * NP + (int)pos] = i;
}

__global__ __launch_bounds__(BLK) void speaker_kernel(const float* __restrict__ emb,
                                                      const int* __restrict__ members,
                                                      float* __restrict__ contribs) {
    __shared__ float sm[4][NP];
    __shared__ float sm2[4];

    const int s = blockIdx.x;
    const int t = threadIdx.x;
    const int lane = t & 63;
    const int wid  = t >> 6;

    // ---- Prologue: uniform member load + in-register Batcher sort (no LDS, no barriers) ----
    int m[NP];
    #pragma unroll
    for (int k = 0; k < NP; ++k) m[k] = members[s * NP + k];
    // 19-comparator odd-even mergesort network, all indices compile-time constant
    #define CE(a, b) { int lo_ = min(m[a], m[b]); int hi_ = max(m[a], m[b]); m[a] = lo_; m[b] = hi_; }
    CE(0,1) CE(2,3) CE(4,5) CE(6,7)
    CE(0,2) CE(1,3) CE(4,6) CE(5,7)
    CE(1,2) CE(5,6)
    CE(0,4) CE(1,5) CE(2,6) CE(3,7)
    CE(2,4) CE(3,5)
    CE(1,2) CE(3,4) CE(5,6)
    #undef CE

    // ---- Phase 1: issue ALL 16 loads (8 rows x 2 float4) before any use ----
    float4 x0[NP], x1[NP];
    #pragma unroll
    for (int k = 0; k < NP; ++k) {
        const float4* row = (const float4*)(emb + (size_t)m[k] * D);
        x0[k] = row[t];
        x1[k] = row[t + BLK];
    }

    // ---- Phase 2: per-row partial sumsq + wave-level reduce (no barriers) ----
    float ss[NP];
    #pragma unroll
    for (int k = 0; k < NP; ++k) {
        float v = x0[k].x * x0[k].x + x0[k].y * x0[k].y
                + x0[k].z * x0[k].z + x0[k].w * x0[k].w
                + x1[k].x * x1[k].x + x1[k].y * x1[k].y
                + x1[k].z * x1[k].z + x1[k].w * x1[k].w;
        #pragma unroll
        for (int o = 32; o > 0; o >>= 1) v += __shfl_xor(v, o, 64);
        ss[k] = v;
    }

    // ---- Phase 3: one barrier pair for all 8 cross-wave reductions ----
    if (lane == 0) {
        #pragma unroll
        for (int k = 0; k < NP; ++k) sm[wid][k] = ss[k];
    }
    __syncthreads();

    // ---- Phase 4: normalize + accumulate speaker-sum in registers ----
    float4 a0 = make_float4(0.f, 0.f, 0.f, 0.f);
    float4 a1 = make_float4(0.f, 0.f, 0.f, 0.f);
    float selfsum = 0.f;  // sum of ||e_hat||^2 (uniform across threads)
    #pragma unroll
    for (int k = 0; k < NP; ++k) {
        float tot = sm[0][k] + sm[1][k] + sm[2][k] + sm[3][k];
        float inv = rsqrtf(tot + EPSF);
        selfsum += tot * inv * inv;
        a0.x += x0[k].x * inv; a0.y += x0[k].y * inv;
        a0.z += x0[k].z * inv; a0.w += x0[k].w * inv;
        a1.x += x1[k].x * inv; a1.y += x1[k].y * inv;
        a1.z += x1[k].z * inv; a1.w += x1[k].w * inv;
    }

    // ---- Phase 5: ||sum||^2 reduce + write contribution ----
    float nq = a0.x * a0.x + a0.y * a0.y + a0.z * a0.z + a0.w * a0.w
             + a1.x * a1.x + a1.y * a1.y + a1.z * a1.z + a1.w * a1.w;
    #pragma unroll
    for (int o = 32; o > 0; o >>= 1) nq += __shfl_xor(nq, o, 64);
    if (lane == 0) sm2[wid] = nq;
    __syncthreads();

    if (t == 0) {
        float total_nq   = sm2[0] + sm2[1] + sm2[2] + sm2[3];
        float sumpair    = 0.5f * (total_nq - selfsum);       // sum_{i<j} cos sim
        float n_pairs    = (float)(NP * (NP - 1)) * 0.5f;     // 28
        float mean_intra = 1.0f - sumpair / n_pairs;
        float c          = mean_intra - MARGINF;
        contribs[s] = c > 0.f ? c : 0.f;                      // plain store
    }
}

__global__ __launch_bounds__(1024) void final_reduce_kernel(const float* __restrict__ contribs,
                                                            float* __restrict__ out) {
    __shared__ float sm[16];
    int t = threadIdx.x;
    float v = contribs[t] + contribs[t + 1024] + contribs[t + 2048] + contribs[t + 3072];
    #pragma unroll
    for (int o = 32; o > 0; o >>= 1) v += __shfl_xor(v, o, 64);
    int lane = t & 63, wid = t >> 6;
    if (lane == 0) sm[wid] = v;
    __syncthreads();
    if (t == 0) {
        float r = 0.f;
        #pragma unroll
        for (int i = 0; i < 16; ++i) r += sm[i];
        *out = r / (float)S;
    }
}

extern "C" void kernel_launch(void* const* d_in, const int* in_sizes, int n_in,
                              void* d_out, int out_size, void* d_ws, size_t ws_size,
                              hipStream_t stream) {
    const float* emb    = (const float*)d_in[0];
    const int*   labels = (const int*)d_in[1];
    float*       out    = (float*)d_out;

    char* ws = (char*)d_ws;
    unsigned int* counts   = (unsigned int*)ws;                           // S uints (never zeroed)
    int*          members  = (int*)(ws + (size_t)S * sizeof(int));        // S*NP ints
    float*        contribs = (float*)(ws + (size_t)S * sizeof(int)
                                         + (size_t)S * NP * sizeof(int)); // S floats

    const int B = in_sizes[1];   // 32768

    gather_kernel<<<(B + 255) / 256, 256, 0, stream>>>(labels, counts, members, B);
    speaker_kernel<<<S, BLK, 0, stream>>>(emb, members, contribs);
    final_reduce_kernel<<<1, 1024, 0, stream>>>(contribs, out);
}